// Round 12
// baseline (424.538 us; speedup 1.0000x reference)
//
#include <hip/hip_runtime.h>

#define NN 100000
#define NE 3200000
#define FIN 128
#define HID 32
#define MH  64
#define NC  10
#define NG  64
#define NBKT 782           // ceil(NN/128) buckets of 128 dest nodes
#define NBLK 512           // edge-pass blocks
#define EPB  (NE / NBLK)   // 6250 edges per block
#define SCANL (NBKT * NBLK)
#define SRCMASK 0x1FFFF    // src < 100000 < 2^17
#define BCAP 5120          // bucket LDS capacity (mean 4092, sd ~64)

typedef float floatx2 __attribute__((ext_vector_type(2)));

__global__ void init_misc(float* __restrict__ sc) {
    int i = blockIdx.x * 256 + threadIdx.x;
    if (i < NG * HID + NG) sc[i] = 0.0f;
}

// per-block LDS histogram over 782 dest-buckets; no global atomics
__global__ __launch_bounds__(1024)
void hist_bkt(const int* __restrict__ ei, int* __restrict__ cnt2) {
    __shared__ int h[NBKT];
    int tid = threadIdx.x, blk = blockIdx.x;
    for (int b = tid; b < NBKT; b += 1024) h[b] = 0;
    __syncthreads();
    int base = blk * EPB;
    for (int i = tid; i < EPB; i += 1024)
        atomicAdd(&h[ei[NE + base + i] >> 7], 1);
    __syncthreads();
    for (int b = tid; b < NBKT; b += 1024) cnt2[b * NBLK + blk] = h[b];
}

// ---- generic exclusive scan (1024 elems/block) ----
__global__ void scan_block(const int* __restrict__ in, int* __restrict__ out,
                           int* __restrict__ bsum, int n) {
    __shared__ int lds[256];
    int tid = threadIdx.x;
    int base = blockIdx.x * 1024 + tid * 4;
    int v0 = 0, v1 = 0, v2 = 0, v3 = 0;
    if (base + 0 < n) v0 = in[base + 0];
    if (base + 1 < n) v1 = in[base + 1];
    if (base + 2 < n) v2 = in[base + 2];
    if (base + 3 < n) v3 = in[base + 3];
    int s = v0 + v1 + v2 + v3;
    lds[tid] = s;
    __syncthreads();
    for (int off = 1; off < 256; off <<= 1) {
        int val = (tid >= off) ? lds[tid - off] : 0;
        __syncthreads();
        lds[tid] += val;
        __syncthreads();
    }
    int excl = lds[tid] - s;
    if (tid == 255) bsum[blockIdx.x] = lds[255];
    if (base + 0 < n) out[base + 0] = excl;
    if (base + 1 < n) out[base + 1] = excl + v0;
    if (base + 2 < n) out[base + 2] = excl + v0 + v1;
    if (base + 3 < n) out[base + 3] = excl + v0 + v1 + v2;
}

// wave-parallel exclusive scan of bsum (chunked shuffle scan with carry)
__global__ void scan_top(int* __restrict__ bsum, int nb) {
    int lane = threadIdx.x;  // 64 threads
    int carry = 0;
    for (int base = 0; base < nb; base += 64) {
        int i = base + lane;
        int orig = (i < nb) ? bsum[i] : 0;
        int v = orig;
#pragma unroll
        for (int off = 1; off < 64; off <<= 1) {
            int t = __shfl_up(v, off, 64);
            if (lane >= off) v += t;
        }
        if (i < nb) bsum[i] = carry + v - orig;   // exclusive
        carry += __shfl(v, 63, 64);
    }
}

__global__ void scan_add(int* __restrict__ data, const int* __restrict__ bsum, int n) {
    int i = blockIdx.x * 256 + threadIdx.x;
    if (i < n) data[i] += bsum[i >> 10];
}

// single global read: pack each edge into LDS at its sorted slot, then
// slot-major burst writes to tre.
__global__ __launch_bounds__(1024)
void scatter_bkt(const int* __restrict__ ei, const float* __restrict__ ew,
                 const int* __restrict__ cnt2, const int* __restrict__ scanned,
                 int2* __restrict__ tre) {
    __shared__ int2 pay[EPB];      // 50 KB
    __shared__ int scur[NBKT];
    __shared__ int hexc[NBKT];
    __shared__ int gbase[NBKT];
    int tid = threadIdx.x, blk = blockIdx.x;
    int myh = 0;
    if (tid < NBKT) {
        myh = cnt2[tid * NBLK + blk];
        gbase[tid] = scanned[tid * NBLK + blk];
        scur[tid] = myh;
    }
    __syncthreads();
    for (int off = 1; off < NBKT; off <<= 1) {
        int v = (tid < NBKT && tid >= off) ? scur[tid - off] : 0;
        __syncthreads();
        if (tid < NBKT) scur[tid] += v;
        __syncthreads();
    }
    if (tid < NBKT) { int ex = scur[tid] - myh; hexc[tid] = ex; scur[tid] = ex; }
    __syncthreads();
    int base = blk * EPB;
    for (int i = tid; i < EPB; i += 1024) {
        int e = base + i;
        int c = ei[NE + e];
        int r = ei[e];
        unsigned int wb = __float_as_uint(ew[e]);
        int b = c >> 7;
        int j = atomicAdd(&scur[b], 1);
        pay[j] = make_int2(r | ((c & 127) << 17) | ((b & 0xFF) << 24),
                           (int)((wb & ~3u) | ((unsigned)b >> 8)));
    }
    __syncthreads();
    for (int j = tid; j < EPB; j += 1024) {
        int2 q = pay[j];
        int b = (int)((((unsigned)q.y & 3u) << 8) | (((unsigned)q.x >> 24) & 0xFFu));
        int pos = gbase[b] + (j - hexc[b]);
        tre[pos] = make_int2(q.x & 0x00FFFFFF, q.y & ~3);
    }
}

// per bucket: stream tre, LDS-accumulate weighted in-degree, write dinv
__global__ __launch_bounds__(512)
void deg_k(const int2* __restrict__ tre, const int* __restrict__ scanned,
           float* __restrict__ dinv) {
    __shared__ float dw[128];
    int b = blockIdx.x, tid = threadIdx.x;
    int base = scanned[b * NBLK];
    int end = (b == NBKT - 1) ? NE : scanned[(b + 1) * NBLK];
    if (tid < 128) dw[tid] = 0.f;
    __syncthreads();
    for (int i = base + tid; i < end; i += 512) {
        int2 q = tre[i];
        atomicAdd(&dw[(q.x >> 17) & 127], __int_as_float(q.y));
    }
    __syncthreads();
    if (tid < 128) {
        int node = b * 128 + tid;
        if (node < NN) dinv[node] = rsqrtf(1.0f + dw[tid]);
    }
}

// per bucket: stage in LDS, 128-bin count+scan, emit node-sorted 4B packed
// edges: src(17b) | sign-free bf16 of (ew*dinv[src]) (15b). Also rowptr.
__global__ __launch_bounds__(512)
void sort_k(const int2* __restrict__ tre, const int* __restrict__ scanned,
            const float* __restrict__ dinv,
            unsigned int* __restrict__ srn4, int* __restrict__ rowptr) {
    __shared__ int2 ed[BCAP];      // 40 KB
    __shared__ int h[128];
    __shared__ int sc[128];
    __shared__ int cur[128];
    int b = blockIdx.x, tid = threadIdx.x;
    int base = scanned[b * NBLK];
    int end = (b == NBKT - 1) ? NE : scanned[(b + 1) * NBLK];
    int n = end - base;
    bool staged = (n <= BCAP);
    if (tid < 128) h[tid] = 0;
    if (staged)
        for (int i = tid; i < n; i += 512) ed[i] = tre[base + i];
    __syncthreads();
    for (int i = tid; i < n; i += 512) {
        int2 q = staged ? ed[i] : tre[base + i];
        atomicAdd(&h[(q.x >> 17) & 127], 1);
    }
    __syncthreads();
    if (tid < 128) sc[tid] = h[tid];
    __syncthreads();
    for (int off = 1; off < 128; off <<= 1) {
        int v = (tid < 128 && tid >= off) ? sc[tid - off] : 0;
        __syncthreads();
        if (tid < 128) sc[tid] += v;
        __syncthreads();
    }
    if (tid < 128) {
        int node = b * 128 + tid;
        if (node < NN) rowptr[node] = base + sc[tid];     // end offset
        cur[tid] = base + sc[tid] - h[tid];               // start cursor
    }
    __syncthreads();
    for (int i = tid; i < n; i += 512) {
        int2 q = staged ? ed[i] : tre[base + i];
        int key = (q.x >> 17) & 127;
        int pos = atomicAdd(&cur[key], 1);
        unsigned int src = (unsigned)(q.x & SRCMASK);
        float w = __int_as_float(q.y) * dinv[src];
        unsigned int wb = __float_as_uint(w);
        wb += 0x7FFFu + ((wb >> 16) & 1u);               // RNE to bf16
        srn4[pos] = src | (((wb >> 16) & 0x7FFFu) << 17);
    }
}

// LDS-tiled linear: 64-row x tile (padded, coalesced staging, relu folded),
// W pre-swizzled to wp[j*8+kg] = W[j][4kg..4kg+3]; thread = 2 rows x 4
// CONTIGUOUS cols; output packed to fp8 e4m3 (one 4B word per row per thread).
template <int IN_DIM, bool RELU_IN>
__global__ __launch_bounds__(256)
void linear_k(const float* __restrict__ in, const float* __restrict__ W,
              unsigned int* __restrict__ tmp8) {
    constexpr int J4 = IN_DIM / 4;       // 32 or 8
    constexpr int XSS = J4 + 1;          // padded row stride (float4)
    __shared__ float4 xs[64 * XSS];
    __shared__ float4 wp[IN_DIM * 8];
    int tid = threadIdx.x;
    for (int idx = tid; idx < IN_DIM * 8; idx += 256) {
        int j = idx >> 3, kg = idx & 7;
        const float* wr = W + j * 32 + kg * 4;
        wp[idx] = make_float4(wr[0], wr[1], wr[2], wr[3]);
    }
    int rbase = blockIdx.x * 64;
    const float4* in4 = (const float4*)in;
    for (int idx = tid; idx < 64 * J4; idx += 256) {
        int row = idx / J4, j4 = idx % J4;
        int grow = rbase + row;
        float4 v = (grow < NN) ? in4[(size_t)grow * J4 + j4]
                               : make_float4(0.f, 0.f, 0.f, 0.f);
        if (RELU_IN) {
            v.x = fmaxf(v.x, 0.f); v.y = fmaxf(v.y, 0.f);
            v.z = fmaxf(v.z, 0.f); v.w = fmaxf(v.w, 0.f);
        }
        xs[row * XSS + j4] = v;
    }
    __syncthreads();
    int kg = tid & 7;          // cols 4kg..4kg+3
    int rp = tid >> 3;         // rows 2rp, 2rp+1
    int r0 = rbase + 2 * rp;
    if (r0 >= NN) return;
    const float4* x0 = &xs[(2 * rp) * XSS];
    const float4* x1 = &xs[(2 * rp + 1) * XSS];
    float a00 = 0, a01 = 0, a02 = 0, a03 = 0;
    float a10 = 0, a11 = 0, a12 = 0, a13 = 0;
#pragma unroll
    for (int j4 = 0; j4 < J4; ++j4) {
        float4 v0 = x0[j4], v1 = x1[j4];
        const float4* wj = &wp[j4 * 4 * 8 + kg];
        float4 w0 = wj[0], w1 = wj[8], w2 = wj[16], w3 = wj[24];
#define LSTEP(VX0, VX1, W4) \
        a00 = fmaf(VX0, W4.x, a00); a01 = fmaf(VX0, W4.y, a01); \
        a02 = fmaf(VX0, W4.z, a02); a03 = fmaf(VX0, W4.w, a03); \
        a10 = fmaf(VX1, W4.x, a10); a11 = fmaf(VX1, W4.y, a11); \
        a12 = fmaf(VX1, W4.z, a12); a13 = fmaf(VX1, W4.w, a13);
        LSTEP(v0.x, v1.x, w0)
        LSTEP(v0.y, v1.y, w1)
        LSTEP(v0.z, v1.z, w2)
        LSTEP(v0.w, v1.w, w3)
#undef LSTEP
    }
    int q0 = __builtin_amdgcn_cvt_pk_fp8_f32(a00, a01, 0, false);
    q0 = __builtin_amdgcn_cvt_pk_fp8_f32(a02, a03, q0, true);
    int q1 = __builtin_amdgcn_cvt_pk_fp8_f32(a10, a11, 0, false);
    q1 = __builtin_amdgcn_cvt_pk_fp8_f32(a12, a13, q1, true);
    tmp8[r0 * 8 + kg] = (unsigned int)q0;
    tmp8[(r0 + 1) * 8 + kg] = (unsigned int)q1;
}

// one wave per dest node: 16 edge slots x 4 feat-octets (uint2 = 8 fp8/lane).
// ONE coalesced preload of the node's first 64 edge records, then __shfl
// (no dependent srn4->tmp8 load chain); up to 64 gathers in flight.
__global__ void aggregate(const unsigned int* __restrict__ srn4,
                          const int* __restrict__ rowptr,
                          const float* __restrict__ dinv,
                          const float* __restrict__ bias,
                          const uint2* __restrict__ tmp8v,   // row = 4 uint2 (32B)
                          float* __restrict__ h) {
    int wid = (blockIdx.x * 256 + threadIdx.x) >> 6;
    if (wid >= NN) return;
    int lane = threadIdx.x & 63;
    int g = lane >> 2;      // edge slot 0..15
    int q = lane & 3;       // feat octet (feats 8q..8q+7)
    int end = rowptr[wid];
    int start = (wid == 0) ? 0 : rowptr[wid - 1];
    int n = end - start;
    unsigned int pre = 0;
    if (lane < n) pre = srn4[start + lane];
    float a0 = 0, a1 = 0, a2 = 0, a3 = 0, a4 = 0, a5 = 0, a6 = 0, a7 = 0;
#pragma unroll
    for (int i = 0; i < 4; ++i) {
        int j = g + 16 * i;
        if (j < n) {
            unsigned int p = __shfl((int)pre, j, 64);
            float w = __uint_as_float((p >> 1) & 0x7FFF0000u);
            uint2 u = tmp8v[(size_t)(p & SRCMASK) * 4 + q];
            floatx2 f0 = __builtin_amdgcn_cvt_pk_f32_fp8(u.x, false);
            floatx2 f1 = __builtin_amdgcn_cvt_pk_f32_fp8(u.x, true);
            floatx2 f2 = __builtin_amdgcn_cvt_pk_f32_fp8(u.y, false);
            floatx2 f3 = __builtin_amdgcn_cvt_pk_f32_fp8(u.y, true);
            a0 = fmaf(w, f0.x, a0); a1 = fmaf(w, f0.y, a1);
            a2 = fmaf(w, f1.x, a2); a3 = fmaf(w, f1.y, a3);
            a4 = fmaf(w, f2.x, a4); a5 = fmaf(w, f2.y, a5);
            a6 = fmaf(w, f3.x, a6); a7 = fmaf(w, f3.y, a7);
        }
    }
    // rare tail: degree > 64
    for (int e = start + 64 + g; e < end; e += 16) {
        unsigned int p = srn4[e];
        float w = __uint_as_float((p >> 1) & 0x7FFF0000u);
        uint2 u = tmp8v[(size_t)(p & SRCMASK) * 4 + q];
        floatx2 f0 = __builtin_amdgcn_cvt_pk_f32_fp8(u.x, false);
        floatx2 f1 = __builtin_amdgcn_cvt_pk_f32_fp8(u.x, true);
        floatx2 f2 = __builtin_amdgcn_cvt_pk_f32_fp8(u.y, false);
        floatx2 f3 = __builtin_amdgcn_cvt_pk_f32_fp8(u.y, true);
        a0 = fmaf(w, f0.x, a0); a1 = fmaf(w, f0.y, a1);
        a2 = fmaf(w, f1.x, a2); a3 = fmaf(w, f1.y, a3);
        a4 = fmaf(w, f2.x, a4); a5 = fmaf(w, f2.y, a5);
        a6 = fmaf(w, f3.x, a6); a7 = fmaf(w, f3.y, a7);
    }
    // reduce over 16 slots (lanes at stride 4 share a feat octet)
#pragma unroll
    for (int m = 4; m <= 32; m <<= 1) {
        a0 += __shfl_xor(a0, m, 64); a1 += __shfl_xor(a1, m, 64);
        a2 += __shfl_xor(a2, m, 64); a3 += __shfl_xor(a3, m, 64);
        a4 += __shfl_xor(a4, m, 64); a5 += __shfl_xor(a5, m, 64);
        a6 += __shfl_xor(a6, m, 64); a7 += __shfl_xor(a7, m, 64);
    }
    if (g == 0) {
        float d = dinv[wid];
        float d2 = d * d;
        uint2 sv = tmp8v[(size_t)wid * 4 + q];
        floatx2 s0 = __builtin_amdgcn_cvt_pk_f32_fp8(sv.x, false);
        floatx2 s1 = __builtin_amdgcn_cvt_pk_f32_fp8(sv.x, true);
        floatx2 s2 = __builtin_amdgcn_cvt_pk_f32_fp8(sv.y, false);
        floatx2 s3 = __builtin_amdgcn_cvt_pk_f32_fp8(sv.y, true);
        const float4* b4 = (const float4*)bias;
        float4 bq0 = b4[2 * q], bq1 = b4[2 * q + 1];
        float4 o0, o1;
        o0.x = bq0.x + d2 * s0.x + d * a0;
        o0.y = bq0.y + d2 * s0.y + d * a1;
        o0.z = bq0.z + d2 * s1.x + d * a2;
        o0.w = bq0.w + d2 * s1.y + d * a3;
        o1.x = bq1.x + d2 * s2.x + d * a4;
        o1.y = bq1.y + d2 * s2.y + d * a5;
        o1.z = bq1.z + d2 * s3.x + d * a6;
        o1.w = bq1.w + d2 * s3.y + d * a7;
        float4* hp = (float4*)(h + (size_t)wid * HID);
        hp[2 * q] = o0;
        hp[2 * q + 1] = o1;
    }
}

// sorted-batch run-length pooling
__global__ void pool_k(const float* __restrict__ h, const int* __restrict__ batch,
                       float* __restrict__ sums, float* __restrict__ counts) {
    int t = blockIdx.x * 256 + threadIdx.x;
    int chunk = t >> 5, k = t & 31;
    int n0 = chunk * 32;
    if (n0 >= NN) return;
    int n1 = min(n0 + 32, NN);
    int g = batch[n0];
    float acc = 0.f, cacc = 0.f;
    for (int i = n0; i < n1; ++i) {
        int gi = batch[i];
        if (gi != g) {
            atomicAdd(&sums[g * HID + k], acc);
            if (k == 0) atomicAdd(&counts[g], cacc);
            g = gi; acc = 0.f; cacc = 0.f;
        }
        acc += h[(size_t)i * HID + k];
        cacc += 1.f;
    }
    atomicAdd(&sums[g * HID + k], acc);
    if (k == 0) atomicAdd(&counts[g], cacc);
}

// MLP: one block per graph, one wave; thread k owns output column k.
__global__ __launch_bounds__(64)
void mlp_k(const float* __restrict__ sums, const float* __restrict__ counts,
           const float* __restrict__ Wm0, const float* __restrict__ bm0,
           const float* __restrict__ Wm1, const float* __restrict__ bm1,
           const float* __restrict__ Wout, const float* __restrict__ bout,
           float* __restrict__ out) {
    __shared__ float g0[HID];
    __shared__ float g1[MH];
    __shared__ float g2[MH];
    int g = blockIdx.x;       // 0..63
    int k = threadIdx.x;      // 0..63
    if (k < HID) g0[k] = sums[g * HID + k] / fmaxf(counts[g], 1.0f);
    __syncthreads();
    float acc = bm0[k];
#pragma unroll
    for (int j = 0; j < HID; ++j) acc = fmaf(g0[j], Wm0[j * MH + k], acc);
    g1[k] = fmaxf(acc, 0.f);
    __syncthreads();
    float acc2 = bm1[k];
#pragma unroll
    for (int j = 0; j < MH; ++j) acc2 = fmaf(g1[j], Wm1[j * MH + k], acc2);
    g2[k] = fmaxf(acc2, 0.f);
    __syncthreads();
    if (k < NC) {
        float acc3 = bout[k];
#pragma unroll
        for (int j = 0; j < MH; ++j) acc3 = fmaf(g2[j], Wout[j * NC + k], acc3);
        out[g * NC + k] = acc3;
    }
}

extern "C" void kernel_launch(void* const* d_in, const int* in_sizes, int n_in,
                              void* d_out, int out_size, void* d_ws, size_t ws_size,
                              hipStream_t stream) {
    const float* x    = (const float*)d_in[0];
    const int*   ei   = (const int*)d_in[1];
    const float* ew   = (const float*)d_in[2];
    const int*   batch= (const int*)d_in[3];
    const float* W1   = (const float*)d_in[4];
    const float* b1   = (const float*)d_in[5];
    const float* W2   = (const float*)d_in[6];
    const float* b2   = (const float*)d_in[7];
    const float* W3   = (const float*)d_in[8];
    const float* b3   = (const float*)d_in[9];
    const float* Wm0  = (const float*)d_in[10];
    const float* bm0  = (const float*)d_in[11];
    const float* Wm1  = (const float*)d_in[12];
    const float* bm1  = (const float*)d_in[13];
    const float* Wout = (const float*)d_in[14];
    const float* bout = (const float*)d_in[15];
    float* out = (float*)d_out;

    // workspace: srn4 | S (tre+cnt2+scanned <-> tmp8+hA+hB) | small bufs
    char* p = (char*)d_ws;
    unsigned int* srn4 = (unsigned int*)p; p += sizeof(unsigned int) * (size_t)NE; // 12.8 MB
    char*  S   = p;                      p += 12 * (size_t)NE;                // 38.4 MB shared
    int2*  tre = (int2*)S;                                                    // 25.6 MB
    int*   cnt2    = (int*)(S + sizeof(int2) * (size_t)NE);                   // 1.6 MB (dies pre-layer1)
    int*   scanned = cnt2 + SCANL;                                            // 1.6 MB
    unsigned int* tmp8 = (unsigned int*)S;                                    // 3.2 MB
    float* hA  = (float*)(S + (size_t)NN * HID);                              // 12.8 MB
    float* hB  = hA + (size_t)NN * HID;                                       // 12.8 MB
    int*   bsum    = (int*)p;            p += sizeof(int) * 512;
    float* dinv    = (float*)p;          p += sizeof(float) * NN;
    int*   rowptr  = (int*)p;            p += sizeof(int) * NN;
    float* sums    = (float*)p;          p += sizeof(float) * NG * HID;
    float* counts  = (float*)p;

    dim3 blk(256);
    const int NB_SCAN = (SCANL + 1023) / 1024;  // 391
    const int NB_LIN = (NN + 63) / 64;          // 1563

    init_misc<<<9, blk, 0, stream>>>(sums);
    hist_bkt<<<NBLK, 1024, 0, stream>>>(ei, cnt2);
    scan_block<<<NB_SCAN, blk, 0, stream>>>(cnt2, scanned, bsum, SCANL);
    scan_top<<<1, 64, 0, stream>>>(bsum, NB_SCAN);
    scan_add<<<(SCANL + 255) / 256, blk, 0, stream>>>(scanned, bsum, SCANL);
    scatter_bkt<<<NBLK, 1024, 0, stream>>>(ei, ew, cnt2, scanned, tre);
    deg_k<<<NBKT, 512, 0, stream>>>(tre, scanned, dinv);
    sort_k<<<NBKT, 512, 0, stream>>>(tre, scanned, dinv, srn4, rowptr);

    // layer 1
    linear_k<FIN, false><<<NB_LIN, blk, 0, stream>>>(x, W1, tmp8);
    aggregate<<<25000, blk, 0, stream>>>(srn4, rowptr, dinv, b1, (const uint2*)tmp8, hA);
    // layer 2
    linear_k<HID, true><<<NB_LIN, blk, 0, stream>>>(hA, W2, tmp8);
    aggregate<<<25000, blk, 0, stream>>>(srn4, rowptr, dinv, b2, (const uint2*)tmp8, hB);
    // layer 3
    linear_k<HID, true><<<NB_LIN, blk, 0, stream>>>(hB, W3, tmp8);
    aggregate<<<25000, blk, 0, stream>>>(srn4, rowptr, dinv, b3, (const uint2*)tmp8, hA);

    pool_k<<<391, blk, 0, stream>>>(hA, batch, sums, counts);
    mlp_k<<<NG, 64, 0, stream>>>(sums, counts, Wm0, bm0, Wm1, bm1, Wout, bout, out);
}